// Round 1
// baseline (466.785 us; speedup 1.0000x reference)
//
#include <hip/hip_runtime.h>
#include <hip/hip_bf16.h>
#include <stdint.h>

// ---------- types ----------
typedef __bf16 bf16x8 __attribute__((ext_vector_type(8)));
typedef float  f32x4  __attribute__((ext_vector_type(4)));

__device__ __forceinline__ unsigned short f2bf(float f) {
    unsigned u = __builtin_bit_cast(unsigned, f);
    u += 0x7fffu + ((u >> 16) & 1u);   // RNE
    return (unsigned short)(u >> 16);
}

// ---------- fp32 -> bf16 convert (vectorized x4) ----------
__global__ void cvt_bf16(const float* __restrict__ in, unsigned short* __restrict__ out, int n) {
    int i = (blockIdx.x * blockDim.x + threadIdx.x) * 4;
    if (i < n) {
        float4 v = *(const float4*)(in + i);
        ushort4 o;
        o.x = f2bf(v.x); o.y = f2bf(v.y); o.z = f2bf(v.z); o.w = f2bf(v.w);
        *(ushort4*)(out + i) = o;
    }
}

// ---------- GEMM C = A * B^T  (A [M,K] row-major bf16, B [N,K] row-major bf16) ----------
// 128x128 tile, BK=64, 256 threads = 4 waves in 2x2, each wave 64x64 (4x4 frags of 16x16x32)
// MODE 0: scatter to Q/K/V bf16 [B,H,T,HD], scale Q by 0.125
// MODE 1: write fp32 C row-major [M,N]
#define BM 128
#define BN 128
#define BKK 64

template<int MODE>
__global__ void gemm_bt(const unsigned short* __restrict__ A,
                        const unsigned short* __restrict__ Bm,
                        int M, int N, int K,
                        float* __restrict__ Cf,
                        unsigned short* __restrict__ Qo,
                        unsigned short* __restrict__ Ko,
                        unsigned short* __restrict__ Vo) {
    __shared__ __align__(16) unsigned short Als[BM * BKK];
    __shared__ __align__(16) unsigned short Bls[BN * BKK];

    const int tid  = threadIdx.x;
    const int lane = tid & 63;
    const int wave = tid >> 6;
    const int wm = wave >> 1, wn = wave & 1;
    const int m0 = blockIdx.y * BM, n0 = blockIdx.x * BN;
    const int l16 = lane & 15, lg = lane >> 4;

    f32x4 acc[4][4];
#pragma unroll
    for (int i = 0; i < 4; i++)
#pragma unroll
        for (int j = 0; j < 4; j++) acc[i][j] = f32x4{0.f, 0.f, 0.f, 0.f};

    const int r0  = tid >> 3;  // 0..31
    const int c8  = tid & 7;   // 16B chunk

    for (int k0 = 0; k0 < K; k0 += BKK) {
        __syncthreads();
        // stage A and B tiles: 128 rows x 64 cols each, 4 chunks per thread per matrix
#pragma unroll
        for (int i = 0; i < 4; i++) {
            int r = r0 + i * 32;
            uint4 av = *(const uint4*)(A  + (size_t)(m0 + r) * K + k0 + c8 * 8);
            uint4 bv = *(const uint4*)(Bm + (size_t)(n0 + r) * K + k0 + c8 * 8);
            *(uint4*)(Als + r * BKK + c8 * 8) = av;
            *(uint4*)(Bls + r * BKK + c8 * 8) = bv;
        }
        __syncthreads();
#pragma unroll
        for (int ks = 0; ks < 2; ++ks) {
            const int koff = ks * 32 + lg * 8;
            bf16x8 af[4], bfv[4];
#pragma unroll
            for (int mf = 0; mf < 4; ++mf)
                af[mf] = *(const bf16x8*)(Als + (wm * 64 + mf * 16 + l16) * BKK + koff);
#pragma unroll
            for (int nf = 0; nf < 4; ++nf)
                bfv[nf] = *(const bf16x8*)(Bls + (wn * 64 + nf * 16 + l16) * BKK + koff);
#pragma unroll
            for (int mf = 0; mf < 4; ++mf)
#pragma unroll
                for (int nf = 0; nf < 4; ++nf)
                    acc[mf][nf] = __builtin_amdgcn_mfma_f32_16x16x32_bf16(af[mf], bfv[nf], acc[mf][nf], 0, 0, 0);
        }
    }

    // epilogue: C/D layout col = lane&15, row = (lane>>4)*4 + j
#pragma unroll
    for (int mf = 0; mf < 4; ++mf) {
        int gm = m0 + wm * 64 + mf * 16 + (lg << 2);
#pragma unroll
        for (int nf = 0; nf < 4; ++nf) {
            int gn = n0 + wn * 64 + nf * 16 + l16;
            if (MODE == 0) {
                int which = gn >> 10;
                int rem = gn & 1023;
                int h = rem >> 6, d = rem & 63;
                unsigned short* dst = (which == 0) ? Qo : (which == 1) ? Ko : Vo;
                float s = (which == 0) ? 0.125f : 1.0f;
#pragma unroll
                for (int j = 0; j < 4; j++) {
                    int m = gm + j;
                    int b = m >> 11, t = m & 2047;
                    dst[((size_t)((b << 4) + h) * 2048 + t) * 64 + d] = f2bf(acc[mf][nf][j] * s);
                }
            } else {
#pragma unroll
                for (int j = 0; j < 4; j++)
                    Cf[(size_t)(gm + j) * N + gn] = acc[mf][nf][j];
            }
        }
    }
}

// ---------- causal flash attention ----------
// grid (T/128, B*H), 256 threads = 4 waves, each wave owns 32 q-rows.
// KV tiles of 64. K/V^T/P LDS tiles XOR-swizzled ( byte ^= (row&7)<<4 ) -> 2-way conflicts max.
__global__ void attn_fwd(const unsigned short* __restrict__ Q,
                         const unsigned short* __restrict__ Kg,
                         const unsigned short* __restrict__ V,
                         unsigned short* __restrict__ O) {
    __shared__ __align__(16) unsigned short Kls[64 * 64];
    __shared__ __align__(16) unsigned short Vt[64 * 64];   // transposed: [dim][key]
    __shared__ __align__(16) unsigned short Pls[4][32 * 64];

    const int tid = threadIdx.x, lane = tid & 63, wave = tid >> 6;
    const int l16 = lane & 15, lg = lane >> 4;
    const int bh = blockIdx.y;
    const int q0 = blockIdx.x * 128;
    const size_t base = (size_t)bh * 2048 * 64;
    const unsigned short* Qp = Q + base;
    const unsigned short* Kp = Kg + base;
    const unsigned short* Vp = V + base;

    // Q fragments held in registers for the whole kernel
    bf16x8 qf[2][2];
#pragma unroll
    for (int mf = 0; mf < 2; mf++)
#pragma unroll
        for (int ks = 0; ks < 2; ks++)
            qf[mf][ks] = *(const bf16x8*)(Qp + (size_t)(q0 + wave * 32 + mf * 16 + l16) * 64 + ks * 32 + lg * 8);

    float mstate[2][4], lsum[2][4];
    f32x4 oacc[2][4];
#pragma unroll
    for (int mf = 0; mf < 2; mf++)
#pragma unroll
        for (int j = 0; j < 4; j++) { mstate[mf][j] = -INFINITY; lsum[mf][j] = 0.f; }
#pragma unroll
    for (int mf = 0; mf < 2; mf++)
#pragma unroll
        for (int nf = 0; nf < 4; nf++) oacc[mf][nf] = f32x4{0.f, 0.f, 0.f, 0.f};

    const int ktmax  = (q0 + 127) >> 6;
    const int rowlim = q0 + wave * 32 + 31;
    const int sr  = tid >> 3;   // staging row 0..31
    const int sc8 = tid & 7;    // staging 16B chunk

    for (int kt = 0; kt <= ktmax; ++kt) {
        __syncthreads();
        // stage K (swizzled row-major [key][dim]) and V^T (swizzled [dim][key])
#pragma unroll
        for (int i = 0; i < 2; i++) {
            int r = sr + i * 32;   // key within tile
            uint4 kv = *(const uint4*)(Kp + (size_t)(kt * 64 + r) * 64 + sc8 * 8);
            *(uint4*)(Kls + r * 64 + ((sc8 ^ (r & 7)) << 3)) = kv;
            uint4 vv = *(const uint4*)(Vp + (size_t)(kt * 64 + r) * 64 + sc8 * 8);
            const unsigned short* pv = (const unsigned short*)&vv;
#pragma unroll
            for (int j = 0; j < 8; j++) {
                int d = sc8 * 8 + j;
                Vt[d * 64 + (r ^ ((d & 7) << 3))] = pv[j];
            }
        }
        __syncthreads();

        if (kt * 64 <= rowlim) {
            // S = Q K^T   (S cols = keys)
            f32x4 sacc[2][4];
#pragma unroll
            for (int mf = 0; mf < 2; mf++)
#pragma unroll
                for (int nf = 0; nf < 4; nf++) sacc[mf][nf] = f32x4{0.f, 0.f, 0.f, 0.f};
#pragma unroll
            for (int ks = 0; ks < 2; ks++) {
                const int koff = ks * 32 + lg * 8;   // dim offset
                bf16x8 kf[4];
#pragma unroll
                for (int nf = 0; nf < 4; nf++) {
                    int key = nf * 16 + l16;
                    kf[nf] = *(const bf16x8*)(Kls + key * 64 + (koff ^ ((key & 7) << 3)));
                }
#pragma unroll
                for (int mf = 0; mf < 2; mf++)
#pragma unroll
                    for (int nf = 0; nf < 4; nf++)
                        sacc[mf][nf] = __builtin_amdgcn_mfma_f32_16x16x32_bf16(qf[mf][ks], kf[nf], sacc[mf][nf], 0, 0, 0);
            }
            // mask + online softmax per m-frag
#pragma unroll
            for (int mf = 0; mf < 2; mf++) {
                int rowb = q0 + wave * 32 + mf * 16 + (lg << 2);
                if (kt * 64 + 63 > rowb) {
#pragma unroll
                    for (int nf = 0; nf < 4; nf++) {
                        int col = kt * 64 + nf * 16 + l16;
#pragma unroll
                        for (int j = 0; j < 4; j++)
                            if (col > rowb + j) sacc[mf][nf][j] = -INFINITY;
                    }
                }
#pragma unroll
                for (int j = 0; j < 4; j++) {
                    float x = fmaxf(fmaxf(sacc[mf][0][j], sacc[mf][1][j]), fmaxf(sacc[mf][2][j], sacc[mf][3][j]));
                    x = fmaxf(x, __shfl_xor(x, 1));
                    x = fmaxf(x, __shfl_xor(x, 2));
                    x = fmaxf(x, __shfl_xor(x, 4));
                    x = fmaxf(x, __shfl_xor(x, 8));
                    float mnew  = fmaxf(mstate[mf][j], x);
                    float alpha = __expf(mstate[mf][j] - mnew);
                    mstate[mf][j] = mnew;
                    float rs = 0.f;
#pragma unroll
                    for (int nf = 0; nf < 4; nf++) {
                        float p = __expf(sacc[mf][nf][j] - mnew);
                        sacc[mf][nf][j] = p;
                        rs += p;
                    }
                    rs += __shfl_xor(rs, 1); rs += __shfl_xor(rs, 2);
                    rs += __shfl_xor(rs, 4); rs += __shfl_xor(rs, 8);
                    lsum[mf][j] = lsum[mf][j] * alpha + rs;
#pragma unroll
                    for (int nf = 0; nf < 4; nf++) oacc[mf][nf][j] *= alpha;
                }
                // write P (bf16) to wave-private swizzled LDS
#pragma unroll
                for (int nf = 0; nf < 4; nf++)
#pragma unroll
                    for (int j = 0; j < 4; j++) {
                        int r = mf * 16 + (lg << 2) + j;
                        int c = nf * 16 + l16;
                        Pls[wave][r * 64 + (c ^ ((r & 7) << 3))] = f2bf(sacc[mf][nf][j]);
                    }
            }
            // O += P * V
#pragma unroll
            for (int ks = 0; ks < 2; ks++) {
                const int koff = ks * 32 + lg * 8;   // key offset
                bf16x8 pf[2], vf[4];
#pragma unroll
                for (int mf = 0; mf < 2; mf++) {
                    int r = mf * 16 + l16;
                    pf[mf] = *(const bf16x8*)(&Pls[wave][r * 64 + (koff ^ ((r & 7) << 3))]);
                }
#pragma unroll
                for (int nf = 0; nf < 4; nf++) {
                    int d = nf * 16 + l16;
                    vf[nf] = *(const bf16x8*)(Vt + d * 64 + (koff ^ ((d & 7) << 3)));
                }
#pragma unroll
                for (int mf = 0; mf < 2; mf++)
#pragma unroll
                    for (int nf = 0; nf < 4; nf++)
                        oacc[mf][nf] = __builtin_amdgcn_mfma_f32_16x16x32_bf16(pf[mf], vf[nf], oacc[mf][nf], 0, 0, 0);
            }
        }
    }

    // epilogue: write O as bf16 to [B,T,DIM] layout
    const int b = bh >> 4, h = bh & 15;
#pragma unroll
    for (int mf = 0; mf < 2; mf++)
#pragma unroll
        for (int j = 0; j < 4; j++) {
            float inv = 1.f / lsum[mf][j];
            int t = q0 + wave * 32 + mf * 16 + (lg << 2) + j;
#pragma unroll
            for (int nf = 0; nf < 4; nf++) {
                int d = nf * 16 + l16;
                O[((size_t)(b * 2048 + t)) * 1024 + h * 64 + d] = f2bf(oacc[mf][nf][j] * inv);
            }
        }
}

// ---------- launch ----------
extern "C" void kernel_launch(void* const* d_in, const int* in_sizes, int n_in,
                              void* d_out, int out_size, void* d_ws, size_t ws_size,
                              hipStream_t stream) {
    const float* x     = (const float*)d_in[0];
    const float* wqkv  = (const float*)d_in[1];
    const float* wproj = (const float*)d_in[2];
    float* out = (float*)d_out;

    const int BT = 4096;          // B*T
    const int DIM = 1024;
    const int NQKV = 3072;

    unsigned short* ws = (unsigned short*)d_ws;
    unsigned short* xb     = ws;                          // 4096*1024  (also reused as attn out)
    unsigned short* wqkvb  = xb + (size_t)BT * DIM;       // 3072*1024
    unsigned short* wprojb = wqkvb + (size_t)NQKV * DIM;  // 1024*1024
    unsigned short* qb     = wprojb + (size_t)DIM * DIM;  // 2*16*2048*64
    unsigned short* kb     = qb + (size_t)BT * DIM;
    unsigned short* vb     = kb + (size_t)BT * DIM;
    unsigned short* attb   = xb;                          // alias: x no longer needed after GEMM1

    // converts
    cvt_bf16<<<(BT * DIM) / 4 / 256, 256, 0, stream>>>(x, xb, BT * DIM);
    cvt_bf16<<<(NQKV * DIM) / 4 / 256, 256, 0, stream>>>(wqkv, wqkvb, NQKV * DIM);
    cvt_bf16<<<(DIM * DIM) / 4 / 256, 256, 0, stream>>>(wproj, wprojb, DIM * DIM);

    // QKV projection
    gemm_bt<0><<<dim3(NQKV / BN, BT / BM), 256, 0, stream>>>(xb, wqkvb, BT, NQKV, DIM,
                                                             nullptr, qb, kb, vb);
    // attention
    attn_fwd<<<dim3(2048 / 128, 32), 256, 0, stream>>>(qb, kb, vb, attb);

    // output projection
    gemm_bt<1><<<dim3(DIM / BN, BT / BM), 256, 0, stream>>>(attb, wprojb, BT, DIM, DIM,
                                                            out, nullptr, nullptr, nullptr);
}

// Round 2
// 222.621 us; speedup vs baseline: 2.0968x; 2.0968x over previous
//
#include <hip/hip_runtime.h>
#include <hip/hip_bf16.h>
#include <stdint.h>

// ---------- types ----------
typedef __bf16 bf16x8 __attribute__((ext_vector_type(8)));
typedef float  f32x4  __attribute__((ext_vector_type(4)));

__device__ __forceinline__ unsigned short f2bf(float f) {
    unsigned u = __builtin_bit_cast(unsigned, f);
    u += 0x7fffu + ((u >> 16) & 1u);   // RNE
    return (unsigned short)(u >> 16);
}

__device__ __forceinline__ void gload16(const void* g, void* l) {
    __builtin_amdgcn_global_load_lds((const __attribute__((address_space(1))) void*)g,
                                     (__attribute__((address_space(3))) void*)l, 16, 0, 0);
}

// ---------- fp32 -> bf16 convert (vectorized x4) ----------
__global__ void cvt_bf16(const float* __restrict__ in, unsigned short* __restrict__ out, int n) {
    int i = (blockIdx.x * blockDim.x + threadIdx.x) * 4;
    if (i < n) {
        float4 v = *(const float4*)(in + i);
        ushort4 o;
        o.x = f2bf(v.x); o.y = f2bf(v.y); o.z = f2bf(v.z); o.w = f2bf(v.w);
        *(ushort4*)(out + i) = o;
    }
}

// ---------- GEMM C = A * B^T  (A [M,K] row-major bf16, B [N,K] row-major bf16) ----------
// 128x128 tile, BK=64, 256 threads = 4 waves in 2x2, each wave 64x64 (4x4 frags of 16x16x32)
// global_load_lds width-16 staging (m97 structure).
// MODE 0: scatter to Q/K/V bf16 [B,H,T,HD], scale Q by 0.125*log2(e) (exp2 softmax downstream)
// MODE 1: write fp32 C row-major [M,N]
#define BM 128
#define BN 128
#define BKK 64

template<int MODE>
__global__ void gemm_bt(const unsigned short* __restrict__ A,
                        const unsigned short* __restrict__ Bm,
                        int M, int N, int K,
                        float* __restrict__ Cf,
                        unsigned short* __restrict__ Qo,
                        unsigned short* __restrict__ Ko,
                        unsigned short* __restrict__ Vo) {
    __shared__ __align__(16) unsigned short Als[BM * BKK];
    __shared__ __align__(16) unsigned short Bls[BN * BKK];

    const int tid  = threadIdx.x;
    const int lane = tid & 63;
    const int wave = tid >> 6;
    const int wm = wave >> 1, wn = wave & 1;
    const int m0 = blockIdx.y * BM, n0 = blockIdx.x * BN;
    const int l16 = lane & 15, lg = lane >> 4;

    f32x4 acc[4][4];
#pragma unroll
    for (int i = 0; i < 4; i++)
#pragma unroll
        for (int j = 0; j < 4; j++) acc[i][j] = f32x4{0.f, 0.f, 0.f, 0.f};

    const int r0 = tid >> 3;   // row 0..31 (wave*8 + lane>>3)
    const int c8 = tid & 7;    // 16B chunk

    for (int k0 = 0; k0 < K; k0 += BKK) {
        __syncthreads();
        // async stage A and B tiles: lane-linear LDS dest, per-lane global src
#pragma unroll
        for (int i = 0; i < 4; i++) {
            gload16(A  + (size_t)(m0 + r0 + i * 32) * K + k0 + c8 * 8,
                    Als + i * 2048 + wave * 512);
            gload16(Bm + (size_t)(n0 + r0 + i * 32) * K + k0 + c8 * 8,
                    Bls + i * 2048 + wave * 512);
        }
        __syncthreads();
#pragma unroll
        for (int ks = 0; ks < 2; ++ks) {
            const int koff = ks * 32 + lg * 8;
            bf16x8 af[4], bfv[4];
#pragma unroll
            for (int mf = 0; mf < 4; ++mf)
                af[mf] = *(const bf16x8*)(Als + (wm * 64 + mf * 16 + l16) * BKK + koff);
#pragma unroll
            for (int nf = 0; nf < 4; ++nf)
                bfv[nf] = *(const bf16x8*)(Bls + (wn * 64 + nf * 16 + l16) * BKK + koff);
#pragma unroll
            for (int mf = 0; mf < 4; ++mf)
#pragma unroll
                for (int nf = 0; nf < 4; ++nf)
                    acc[mf][nf] = __builtin_amdgcn_mfma_f32_16x16x32_bf16(af[mf], bfv[nf], acc[mf][nf], 0, 0, 0);
        }
    }

    // epilogue: C/D layout col = lane&15, row = (lane>>4)*4 + j
#pragma unroll
    for (int mf = 0; mf < 4; ++mf) {
        int gm = m0 + wm * 64 + mf * 16 + (lg << 2);
#pragma unroll
        for (int nf = 0; nf < 4; ++nf) {
            int gn = n0 + wn * 64 + nf * 16 + l16;
            if (MODE == 0) {
                int which = gn >> 10;
                int rem = gn & 1023;
                int h = rem >> 6, d = rem & 63;
                unsigned short* dst = (which == 0) ? Qo : (which == 1) ? Ko : Vo;
                float s = (which == 0) ? 0.180336884f : 1.0f;   // 0.125 * log2(e) for Q
#pragma unroll
                for (int j = 0; j < 4; j++) {
                    int m = gm + j;
                    int b = m >> 11, t = m & 2047;
                    dst[((size_t)((b << 4) + h) * 2048 + t) * 64 + d] = f2bf(acc[mf][nf][j] * s);
                }
            } else {
#pragma unroll
                for (int j = 0; j < 4; j++)
                    Cf[(size_t)(gm + j) * N + gn] = acc[mf][nf][j];
            }
        }
    }
}

// ---------- causal flash attention ----------
// grid (16, B*H): block handles q-tile pair (bx, 31-bx), QBLK=64 (4 waves x 16 rows),
// KVBLK=64. Balanced: every block stages exactly 33 KV tiles, all fully used.
// Register prefetch of next K/V tile hides global latency under compute (T14).
// Swizzles: K chunk^row, V^T col ^ ((j^sc8)<<3) -> conflict-free scalar transpose writes.
__global__ void attn_fwd(const unsigned short* __restrict__ Q,
                         const unsigned short* __restrict__ Kg,
                         const unsigned short* __restrict__ V,
                         unsigned short* __restrict__ O) {
    __shared__ __align__(16) unsigned short Kls[64 * 64];
    __shared__ __align__(16) unsigned short Vt[64 * 64];   // transposed [dim][key], swizzled
    __shared__ __align__(16) unsigned short Pls[4][16 * 64];

    const int tid = threadIdx.x, lane = tid & 63, wave = tid >> 6;
    const int l16 = lane & 15, lg = lane >> 4;
    const int bh = blockIdx.y;
    const int bx = blockIdx.x;
    const size_t base = (size_t)bh * 2048 * 64;
    const unsigned short* Qp = Q + base;
    const unsigned short* Kp = Kg + base;
    const unsigned short* Vp = V + base;
    const int sr  = tid >> 3;   // staging row 0..31
    const int sc8 = tid & 7;    // staging 16B chunk
    const int b = bh >> 4, h = bh & 15;

    for (int pass = 0; pass < 2; ++pass) {
        const int qt = pass ? (31 - bx) : bx;     // q-tile index (64 rows)
        const int q0 = qt * 64;
        const int nt = qt + 1;                    // KV tiles 0..qt

        // Q fragments in registers (Q pre-scaled by 0.125*log2e in GEMM)
        bf16x8 qf[2];
#pragma unroll
        for (int ks = 0; ks < 2; ks++)
            qf[ks] = *(const bf16x8*)(Qp + (size_t)(q0 + wave * 16 + l16) * 64 + ks * 32 + lg * 8);

        float mst[4], lsum[4];
        f32x4 oacc[4];
#pragma unroll
        for (int j = 0; j < 4; j++) { mst[j] = -INFINITY; lsum[j] = 0.f; }
#pragma unroll
        for (int nf = 0; nf < 4; nf++) oacc[nf] = f32x4{0.f, 0.f, 0.f, 0.f};

        // prefetch tile 0
        uint4 kreg[2], vreg[2];
#pragma unroll
        for (int i = 0; i < 2; i++) {
            int r = sr + i * 32;
            kreg[i] = *(const uint4*)(Kp + (size_t)r * 64 + sc8 * 8);
            vreg[i] = *(const uint4*)(Vp + (size_t)r * 64 + sc8 * 8);
        }

        for (int kt = 0; kt < nt; ++kt) {
            __syncthreads();   // previous tile's compute done; LDS reusable
            // write staged regs to LDS
#pragma unroll
            for (int i = 0; i < 2; i++) {
                int r = sr + i * 32;
                *(uint4*)(Kls + r * 64 + ((sc8 ^ (r & 7)) << 3)) = kreg[i];
                const unsigned short* pv = (const unsigned short*)&vreg[i];
#pragma unroll
                for (int j = 0; j < 8; j++) {
                    int d = sc8 * 8 + j;
                    Vt[d * 64 + (r ^ ((j ^ sc8) << 3))] = pv[j];
                }
            }
            __syncthreads();
            // issue next tile's loads early; land under this tile's compute
            if (kt + 1 < nt) {
#pragma unroll
                for (int i = 0; i < 2; i++) {
                    int r = sr + i * 32;
                    kreg[i] = *(const uint4*)(Kp + (size_t)((kt + 1) * 64 + r) * 64 + sc8 * 8);
                    vreg[i] = *(const uint4*)(Vp + (size_t)((kt + 1) * 64 + r) * 64 + sc8 * 8);
                }
            }

            // S = Q K^T : rows = q (lg*4+j), cols = keys (nf*16+l16)
            f32x4 sacc[4];
#pragma unroll
            for (int nf = 0; nf < 4; nf++) sacc[nf] = f32x4{0.f, 0.f, 0.f, 0.f};
#pragma unroll
            for (int ks = 0; ks < 2; ks++) {
                const int koff = ks * 32 + lg * 8;
                bf16x8 kf[4];
#pragma unroll
                for (int nf = 0; nf < 4; nf++) {
                    int key = nf * 16 + l16;
                    kf[nf] = *(const bf16x8*)(Kls + key * 64 + (koff ^ ((key & 7) << 3)));
                }
#pragma unroll
                for (int nf = 0; nf < 4; nf++)
                    sacc[nf] = __builtin_amdgcn_mfma_f32_16x16x32_bf16(qf[ks], kf[nf], sacc[nf], 0, 0, 0);
            }

            // causal mask (diagonal tile only)
            if (kt == qt) {
                int rowb = q0 + wave * 16 + (lg << 2);
#pragma unroll
                for (int nf = 0; nf < 4; nf++) {
                    int col = kt * 64 + nf * 16 + l16;
#pragma unroll
                    for (int j = 0; j < 4; j++)
                        if (col > rowb + j) sacc[nf][j] = -INFINITY;
                }
            }

            // online softmax (base-2 domain; Q pre-scaled by log2e)
#pragma unroll
            for (int j = 0; j < 4; j++) {
                float x = fmaxf(fmaxf(sacc[0][j], sacc[1][j]), fmaxf(sacc[2][j], sacc[3][j]));
                x = fmaxf(x, __shfl_xor(x, 1));
                x = fmaxf(x, __shfl_xor(x, 2));
                x = fmaxf(x, __shfl_xor(x, 4));
                x = fmaxf(x, __shfl_xor(x, 8));
                float mnew  = fmaxf(mst[j], x);
                float alpha = __builtin_amdgcn_exp2f(mst[j] - mnew);
                mst[j] = mnew;
                float rs = 0.f;
#pragma unroll
                for (int nf = 0; nf < 4; nf++) {
                    float p = __builtin_amdgcn_exp2f(sacc[nf][j] - mnew);
                    sacc[nf][j] = p;
                    rs += p;
                }
                rs += __shfl_xor(rs, 1); rs += __shfl_xor(rs, 2);
                rs += __shfl_xor(rs, 4); rs += __shfl_xor(rs, 8);
                lsum[j] = lsum[j] * alpha + rs;
#pragma unroll
                for (int nf = 0; nf < 4; nf++) oacc[nf][j] *= alpha;
            }

            // P (bf16) to wave-private swizzled LDS
#pragma unroll
            for (int nf = 0; nf < 4; nf++)
#pragma unroll
                for (int j = 0; j < 4; j++) {
                    int r = (lg << 2) + j;
                    int c = nf * 16 + l16;
                    Pls[wave][r * 64 + (c ^ ((r & 7) << 3))] = f2bf(sacc[nf][j]);
                }

            // O += P * V
#pragma unroll
            for (int ks = 0; ks < 2; ks++) {
                const int koff = ks * 32 + lg * 8;   // key offset
                bf16x8 pf = *(const bf16x8*)(&Pls[wave][l16 * 64 + (koff ^ ((l16 & 7) << 3))]);
                bf16x8 vf[4];
#pragma unroll
                for (int nf = 0; nf < 4; nf++) {
                    int d = nf * 16 + l16;
                    vf[nf] = *(const bf16x8*)(Vt + d * 64 + (koff ^ (((d & 7) ^ ((d >> 3) & 7)) << 3)));
                }
#pragma unroll
                for (int nf = 0; nf < 4; nf++)
                    oacc[nf] = __builtin_amdgcn_mfma_f32_16x16x32_bf16(pf, vf[nf], oacc[nf], 0, 0, 0);
            }
        }

        // epilogue for this pass: O bf16 to [B,T,DIM]
#pragma unroll
        for (int j = 0; j < 4; j++) {
            float inv = 1.f / lsum[j];
            int t = q0 + wave * 16 + (lg << 2) + j;
#pragma unroll
            for (int nf = 0; nf < 4; nf++) {
                int d = nf * 16 + l16;
                O[((size_t)(b * 2048 + t)) * 1024 + h * 64 + d] = f2bf(oacc[nf][j] * inv);
            }
        }
        __syncthreads();   // LDS safe before next pass restages
    }
}

// ---------- launch ----------
extern "C" void kernel_launch(void* const* d_in, const int* in_sizes, int n_in,
                              void* d_out, int out_size, void* d_ws, size_t ws_size,
                              hipStream_t stream) {
    const float* x     = (const float*)d_in[0];
    const float* wqkv  = (const float*)d_in[1];
    const float* wproj = (const float*)d_in[2];
    float* out = (float*)d_out;

    const int BT = 4096;          // B*T
    const int DIM = 1024;
    const int NQKV = 3072;

    unsigned short* ws = (unsigned short*)d_ws;
    unsigned short* xb     = ws;                          // 4096*1024  (also reused as attn out)
    unsigned short* wqkvb  = xb + (size_t)BT * DIM;       // 3072*1024
    unsigned short* wprojb = wqkvb + (size_t)NQKV * DIM;  // 1024*1024
    unsigned short* qb     = wprojb + (size_t)DIM * DIM;  // 2*16*2048*64
    unsigned short* kb     = qb + (size_t)BT * DIM;
    unsigned short* vb     = kb + (size_t)BT * DIM;
    unsigned short* attb   = xb;                          // alias: x no longer needed after GEMM1

    // converts
    cvt_bf16<<<(BT * DIM) / 4 / 256, 256, 0, stream>>>(x, xb, BT * DIM);
    cvt_bf16<<<(NQKV * DIM) / 4 / 256, 256, 0, stream>>>(wqkv, wqkvb, NQKV * DIM);
    cvt_bf16<<<(DIM * DIM) / 4 / 256, 256, 0, stream>>>(wproj, wprojb, DIM * DIM);

    // QKV projection (Q pre-scaled by 0.125*log2e)
    gemm_bt<0><<<dim3(NQKV / BN, BT / BM), 256, 0, stream>>>(xb, wqkvb, BT, NQKV, DIM,
                                                             nullptr, qb, kb, vb);
    // attention (paired causal tiles, balanced)
    attn_fwd<<<dim3(16, 32), 256, 0, stream>>>(qb, kb, vb, attb);

    // output projection
    gemm_bt<1><<<dim3(DIM / BN, BT / BM), 256, 0, stream>>>(attb, wprojb, BT, DIM, DIM,
                                                            out, nullptr, nullptr, nullptr);
}

// Round 3
// 148.239 us; speedup vs baseline: 3.1489x; 1.5018x over previous
//
#include <hip/hip_runtime.h>
#include <hip/hip_bf16.h>
#include <stdint.h>

// ---------- types ----------
typedef __bf16 bf16x8 __attribute__((ext_vector_type(8)));
typedef float  f32x4  __attribute__((ext_vector_type(4)));
typedef short  short4v __attribute__((ext_vector_type(4)));

__device__ __forceinline__ unsigned short f2bf(float f) {
    unsigned u = __builtin_bit_cast(unsigned, f);
    u += 0x7fffu + ((u >> 16) & 1u);   // RNE
    return (unsigned short)(u >> 16);
}

__device__ __forceinline__ void gload16(const void* g, void* l) {
    __builtin_amdgcn_global_load_lds((const __attribute__((address_space(1))) void*)g,
                                     (__attribute__((address_space(3))) void*)l, 16, 0, 0);
}

// ---------- fp32 -> bf16 convert (vectorized x4) ----------
__global__ void cvt_bf16(const float* __restrict__ in, unsigned short* __restrict__ out, int n) {
    int i = (blockIdx.x * blockDim.x + threadIdx.x) * 4;
    if (i < n) {
        float4 v = *(const float4*)(in + i);
        ushort4 o;
        o.x = f2bf(v.x); o.y = f2bf(v.y); o.z = f2bf(v.z); o.w = f2bf(v.w);
        *(ushort4*)(out + i) = o;
    }
}

// ---------- GEMM C = A * B^T  (A [M,K] row-major bf16, B [N,K] row-major bf16) ----------
#define BM 128
#define BN 128
#define BKK 64

template<int MODE>
__global__ void gemm_bt(const unsigned short* __restrict__ A,
                        const unsigned short* __restrict__ Bm,
                        int M, int N, int K,
                        float* __restrict__ Cf,
                        unsigned short* __restrict__ Qo,
                        unsigned short* __restrict__ Ko,
                        unsigned short* __restrict__ Vo) {
    __shared__ __align__(16) unsigned short Als[BM * BKK];
    __shared__ __align__(16) unsigned short Bls[BN * BKK];

    const int tid  = threadIdx.x;
    const int lane = tid & 63;
    const int wave = tid >> 6;
    const int wm = wave >> 1, wn = wave & 1;
    const int m0 = blockIdx.y * BM, n0 = blockIdx.x * BN;
    const int l16 = lane & 15, lg = lane >> 4;

    f32x4 acc[4][4];
#pragma unroll
    for (int i = 0; i < 4; i++)
#pragma unroll
        for (int j = 0; j < 4; j++) acc[i][j] = f32x4{0.f, 0.f, 0.f, 0.f};

    const int r0 = tid >> 3;   // row 0..31
    const int c8 = tid & 7;    // 16B chunk

    for (int k0 = 0; k0 < K; k0 += BKK) {
        __syncthreads();
#pragma unroll
        for (int i = 0; i < 4; i++) {
            gload16(A  + (size_t)(m0 + r0 + i * 32) * K + k0 + c8 * 8,
                    Als + i * 2048 + wave * 512);
            gload16(Bm + (size_t)(n0 + r0 + i * 32) * K + k0 + c8 * 8,
                    Bls + i * 2048 + wave * 512);
        }
        __syncthreads();
#pragma unroll
        for (int ks = 0; ks < 2; ++ks) {
            const int koff = ks * 32 + lg * 8;
            bf16x8 af[4], bfv[4];
#pragma unroll
            for (int mf = 0; mf < 4; ++mf)
                af[mf] = *(const bf16x8*)(Als + (wm * 64 + mf * 16 + l16) * BKK + koff);
#pragma unroll
            for (int nf = 0; nf < 4; ++nf)
                bfv[nf] = *(const bf16x8*)(Bls + (wn * 64 + nf * 16 + l16) * BKK + koff);
#pragma unroll
            for (int mf = 0; mf < 4; ++mf)
#pragma unroll
                for (int nf = 0; nf < 4; ++nf)
                    acc[mf][nf] = __builtin_amdgcn_mfma_f32_16x16x32_bf16(af[mf], bfv[nf], acc[mf][nf], 0, 0, 0);
        }
    }

#pragma unroll
    for (int mf = 0; mf < 4; ++mf) {
        int gm = m0 + wm * 64 + mf * 16 + (lg << 2);
#pragma unroll
        for (int nf = 0; nf < 4; ++nf) {
            int gn = n0 + wn * 64 + nf * 16 + l16;
            if (MODE == 0) {
                int which = gn >> 10;
                int rem = gn & 1023;
                int h = rem >> 6, d = rem & 63;
                unsigned short* dst = (which == 0) ? Qo : (which == 1) ? Ko : Vo;
                float s = (which == 0) ? 0.180336884f : 1.0f;   // 0.125 * log2(e) for Q
#pragma unroll
                for (int j = 0; j < 4; j++) {
                    int m = gm + j;
                    int b = m >> 11, t = m & 2047;
                    dst[((size_t)((b << 4) + h) * 2048 + t) * 64 + d] = f2bf(acc[mf][nf][j] * s);
                }
            } else {
#pragma unroll
                for (int j = 0; j < 4; j++)
                    Cf[(size_t)(gm + j) * N + gn] = acc[mf][nf][j];
            }
        }
    }
}

// ---------- causal flash attention (swapped QK^T, in-register softmax) ----------
// grid (16, B*H): block handles q-tile pair (bx, 31-bx), QBLK=64 (4 waves x 16 rows).
// S^T = mfma(K_frag, Q_frag): each lane owns ONE q-row (l16), 16 key-values in regs.
// Softmax: 15 reg fmax + 2 shfl (x16, x32); m/l are lane scalars; rescale lane-uniform.
// PV: O^T = mfma(Vt_frag, P_frag). P via packed ds_write_b64, swizzled.
__global__ void attn_fwd(const unsigned short* __restrict__ Q,
                         const unsigned short* __restrict__ Kg,
                         const unsigned short* __restrict__ V,
                         unsigned short* __restrict__ O) {
    __shared__ __align__(16) unsigned short Kls[64 * 64];
    __shared__ __align__(16) unsigned short Vt[64 * 64];   // [dim][key], swizzled
    __shared__ __align__(16) unsigned short Pls[4][16 * 64];

    const int tid = threadIdx.x, lane = tid & 63, wave = tid >> 6;
    const int l16 = lane & 15, lg = lane >> 4;
    const int bh = blockIdx.y;
    const int bx = blockIdx.x;
    const size_t base = (size_t)bh * 2048 * 64;
    const unsigned short* Qp = Q + base;
    const unsigned short* Kp = Kg + base;
    const unsigned short* Vp = V + base;
    const int sr  = tid >> 3;   // staging row 0..31
    const int sc8 = tid & 7;    // staging 16B chunk
    const int b = bh >> 4, h = bh & 15;

    for (int pass = 0; pass < 2; ++pass) {
        const int qt = pass ? (31 - bx) : bx;
        const int q0 = qt * 64;
        const int nt = qt + 1;
        const int qrow = q0 + wave * 16 + l16;   // this lane's q-row (global)

        // Q fragments (B-operand layout; Q pre-scaled by 0.125*log2e)
        bf16x8 qf[2];
#pragma unroll
        for (int ks = 0; ks < 2; ks++)
            qf[ks] = *(const bf16x8*)(Qp + (size_t)qrow * 64 + ks * 32 + lg * 8);

        float mst = -INFINITY, lsum = 0.f;
        f32x4 oacc[4];
#pragma unroll
        for (int nf = 0; nf < 4; nf++) oacc[nf] = f32x4{0.f, 0.f, 0.f, 0.f};

        // prefetch tile 0
        uint4 kreg[2], vreg[2];
#pragma unroll
        for (int i = 0; i < 2; i++) {
            int r = sr + i * 32;
            kreg[i] = *(const uint4*)(Kp + (size_t)r * 64 + sc8 * 8);
            vreg[i] = *(const uint4*)(Vp + (size_t)r * 64 + sc8 * 8);
        }

        for (int kt = 0; kt < nt; ++kt) {
            __syncthreads();
#pragma unroll
            for (int i = 0; i < 2; i++) {
                int r = sr + i * 32;
                *(uint4*)(Kls + r * 64 + ((sc8 ^ (r & 7)) << 3)) = kreg[i];
                const unsigned short* pv = (const unsigned short*)&vreg[i];
#pragma unroll
                for (int j = 0; j < 8; j++) {
                    int d = sc8 * 8 + j;
                    Vt[d * 64 + (r ^ ((j ^ sc8) << 3))] = pv[j];
                }
            }
            __syncthreads();
            if (kt + 1 < nt) {
#pragma unroll
                for (int i = 0; i < 2; i++) {
                    int r = sr + i * 32;
                    kreg[i] = *(const uint4*)(Kp + (size_t)((kt + 1) * 64 + r) * 64 + sc8 * 8);
                    vreg[i] = *(const uint4*)(Vp + (size_t)((kt + 1) * 64 + r) * 64 + sc8 * 8);
                }
            }

            // S^T = K Q^T : lane holds q-row = l16, keys = nf*16 + lg*4 + j
            f32x4 sacc[4];
#pragma unroll
            for (int nf = 0; nf < 4; nf++) sacc[nf] = f32x4{0.f, 0.f, 0.f, 0.f};
#pragma unroll
            for (int ks = 0; ks < 2; ks++) {
                const int koff = ks * 32 + lg * 8;
                bf16x8 kf[4];
#pragma unroll
                for (int nf = 0; nf < 4; nf++) {
                    int key = nf * 16 + l16;
                    kf[nf] = *(const bf16x8*)(Kls + key * 64 + (koff ^ ((key & 7) << 3)));
                }
#pragma unroll
                for (int nf = 0; nf < 4; nf++)
                    sacc[nf] = __builtin_amdgcn_mfma_f32_16x16x32_bf16(kf[nf], qf[ks], sacc[nf], 0, 0, 0);
            }

            // causal mask (diagonal tile only): key > qrow
            if (kt == qt) {
#pragma unroll
                for (int nf = 0; nf < 4; nf++) {
                    int keyb = kt * 64 + nf * 16 + (lg << 2);
#pragma unroll
                    for (int j = 0; j < 4; j++)
                        if (keyb + j > qrow) sacc[nf][j] = -INFINITY;
                }
            }

            // online softmax: in-register row reduce + 2 cross-lane ops
            float xm[4];
#pragma unroll
            for (int nf = 0; nf < 4; nf++)
                xm[nf] = fmaxf(fmaxf(sacc[nf][0], sacc[nf][1]), fmaxf(sacc[nf][2], sacc[nf][3]));
            float x = fmaxf(fmaxf(xm[0], xm[1]), fmaxf(xm[2], xm[3]));
            x = fmaxf(x, __shfl_xor(x, 16));
            x = fmaxf(x, __shfl_xor(x, 32));
            float mnew  = fmaxf(mst, x);
            float alpha = __builtin_amdgcn_exp2f(mst - mnew);
            mst = mnew;
            float ps[4];
#pragma unroll
            for (int nf = 0; nf < 4; nf++) {
#pragma unroll
                for (int j = 0; j < 4; j++)
                    sacc[nf][j] = __builtin_amdgcn_exp2f(sacc[nf][j] - mnew);
                ps[nf] = (sacc[nf][0] + sacc[nf][1]) + (sacc[nf][2] + sacc[nf][3]);
            }
            float rs = (ps[0] + ps[1]) + (ps[2] + ps[3]);
            rs += __shfl_xor(rs, 16);
            rs += __shfl_xor(rs, 32);
            lsum = lsum * alpha + rs;
#pragma unroll
            for (int nf = 0; nf < 4; nf++)
#pragma unroll
                for (int j = 0; j < 4; j++) oacc[nf][j] *= alpha;

            // P -> LDS: row = q (l16), packed 4 keys per ds_write_b64, swizzled
#pragma unroll
            for (int nf = 0; nf < 4; nf++) {
                short4v pk;
#pragma unroll
                for (int j = 0; j < 4; j++) pk[j] = (short)f2bf(sacc[nf][j]);
                int keyb = nf * 16 + (lg << 2);
                *(short4v*)(&Pls[wave][l16 * 64 + (keyb ^ ((l16 & 7) << 3))]) = pk;
            }

            // O^T += V^T P : lane holds q = l16, d = nf*16 + lg*4 + j
#pragma unroll
            for (int ks = 0; ks < 2; ks++) {
                const int koff = ks * 32 + lg * 8;   // key offset
                bf16x8 pf = *(const bf16x8*)(&Pls[wave][l16 * 64 + (koff ^ ((l16 & 7) << 3))]);
                bf16x8 vf[4];
#pragma unroll
                for (int nf = 0; nf < 4; nf++) {
                    int d = nf * 16 + l16;
                    vf[nf] = *(const bf16x8*)(Vt + d * 64 + (koff ^ (((d & 7) ^ ((d >> 3) & 7)) << 3)));
                }
#pragma unroll
                for (int nf = 0; nf < 4; nf++)
                    oacc[nf] = __builtin_amdgcn_mfma_f32_16x16x32_bf16(vf[nf], pf, oacc[nf], 0, 0, 0);
            }
        }

        // epilogue: O^T layout -> O[b, t=qrow, h*64 + d], d = nf*16 + lg*4 + j
        {
            float inv = 1.f / lsum;
            unsigned short* orow = O + ((size_t)(b * 2048 + qrow)) * 1024 + h * 64;
#pragma unroll
            for (int nf = 0; nf < 4; nf++) {
                short4v ov;
#pragma unroll
                for (int j = 0; j < 4; j++) ov[j] = (short)f2bf(oacc[nf][j] * inv);
                *(short4v*)(orow + nf * 16 + (lg << 2)) = ov;
            }
        }
        __syncthreads();
    }
}

// ---------- launch ----------
extern "C" void kernel_launch(void* const* d_in, const int* in_sizes, int n_in,
                              void* d_out, int out_size, void* d_ws, size_t ws_size,
                              hipStream_t stream) {
    const float* x     = (const float*)d_in[0];
    const float* wqkv  = (const float*)d_in[1];
    const float* wproj = (const float*)d_in[2];
    float* out = (float*)d_out;

    const int BT = 4096;          // B*T
    const int DIM = 1024;
    const int NQKV = 3072;

    unsigned short* ws = (unsigned short*)d_ws;
    unsigned short* xb     = ws;
    unsigned short* wqkvb  = xb + (size_t)BT * DIM;
    unsigned short* wprojb = wqkvb + (size_t)NQKV * DIM;
    unsigned short* qb     = wprojb + (size_t)DIM * DIM;
    unsigned short* kb     = qb + (size_t)BT * DIM;
    unsigned short* vb     = kb + (size_t)BT * DIM;
    unsigned short* attb   = xb;

    cvt_bf16<<<(BT * DIM) / 4 / 256, 256, 0, stream>>>(x, xb, BT * DIM);
    cvt_bf16<<<(NQKV * DIM) / 4 / 256, 256, 0, stream>>>(wqkv, wqkvb, NQKV * DIM);
    cvt_bf16<<<(DIM * DIM) / 4 / 256, 256, 0, stream>>>(wproj, wprojb, DIM * DIM);

    gemm_bt<0><<<dim3(NQKV / BN, BT / BM), 256, 0, stream>>>(xb, wqkvb, BT, NQKV, DIM,
                                                             nullptr, qb, kb, vb);
    attn_fwd<<<dim3(16, 32), 256, 0, stream>>>(qb, kb, vb, attb);

    gemm_bt<1><<<dim3(DIM / BN, BT / BM), 256, 0, stream>>>(attb, wprojb, BT, DIM, DIM,
                                                            out, nullptr, nullptr, nullptr);
}